// Round 10
// baseline (34.796 us; speedup 1.0000x reference)
//
#include <hip/hip_runtime.h>
#include <math.h>

#define NH 4    // heads
#define DH 8    // head dim
#define NF 64   // F
#define NT 12   // T
#define NB 2    // batch
#define IT 4    // i-rows tiled per score block (skT reuse factor)

// Branchless exact-gelu: x * 0.5 * (1 + erf(x/sqrt(2))).
// erf via Abramowitz-Stegun 7.1.26 (max abs err 1.5e-7), no divergence.
// R0 vs R2/R4 A/B: identical absmax & time vs OCML erff; VALU fully hidden.
__device__ __forceinline__ float gelu_f(float x) {
    const float s = x * 0.70710678118654752440f;
    const float z = __builtin_fabsf(s);
    const float t = __builtin_amdgcn_rcpf(fmaf(0.3275911f, z, 1.0f));
    float p = fmaf(1.061405429f, t, -1.453152027f);
    p = fmaf(p, t, 1.421413741f);
    p = fmaf(p, t, -0.284496736f);
    p = fmaf(p, t, 0.254829592f);
    p *= t;
    const float e = __builtin_amdgcn_exp2f(z * z * -1.44269504088896340736f); // exp(-z^2)
    const float erfa = fmaf(-p, e, 1.0f);                      // erf(|s|)
    const float erfv = __builtin_copysignf(erfa, s);           // erf(s)
    return 0.5f * x * (1.0f + erfv);
}

// Launch 1: blocks [0, qkBlocks) do qk; blocks [qkBlocks, qkBlocks+N/2) stream
// adj into L2/L3 (asm-kept loads) so the score launch's adj reads are served
// from cache and its DRAM traffic is ~pure-write. (R7 tested this prefetch
// idea but confounded it with cooperative launch, which alone was -133us.)
__global__ __launch_bounds__(256) void qk_prefetch_kernel(
    const float* __restrict__ x, const float* __restrict__ adj,
    const float* __restrict__ w1, const float* __restrict__ W2,
    const float* __restrict__ a,
    float* __restrict__ sqT, float* __restrict__ skT, int N, int qkBlocks)
{
    const int t = threadIdx.x;

    if ((int)blockIdx.x >= qkBlocks) {
        // ---- adj prefetch: 2 rows per block ----
        const int pb = (int)blockIdx.x - qkBlocks;
        const int nq = N >> 2;
        float keep = 0.f;
        #pragma unroll
        for (int r = 0; r < 2; ++r) {
            const int i = pb * 2 + r;
            if (i < N) {
                const float4* arow = (const float4*)(adj + (long long)i * N);
                for (int q = t; q < nq; q += 256) keep += arow[q].x;
            }
        }
        asm volatile("" :: "v"(keep));   // keep loads alive
        return;
    }

    __shared__ float Wq[NF][NH + 1];
    __shared__ float Wk[NF][NH + 1];

    // Fold W2 (64x32) with aq/ak (8 each) -> Wq/Wk (64x4), once per block.
    {
        int f = t >> 2, h = t & 3;
        float accq = 0.f, acck = 0.f;
        #pragma unroll
        for (int k = 0; k < DH; ++k) {
            float w = W2[f * (NH * DH) + h * DH + k];
            accq += w * a[k];
            acck += w * a[DH + k];
        }
        Wq[f][h] = accq;
        Wk[f][h] = acck;
    }
    __syncthreads();

    float w1r[NT];
    #pragma unroll
    for (int i = 0; i < NT; ++i) w1r[i] = w1[i];

    const int wave = t >> 6;
    const int lane = t & 63;                      // = f
    const long long row = (long long)blockIdx.x * 4 + wave;   // in [0, NB*N)
    if (row >= (long long)NB * N) return;

    const float* xr = x + row * (NF * NT) + (long long)lane * NT;
    float4 v0 = *(const float4*)(xr);
    float4 v1 = *(const float4*)(xr + 4);
    float4 v2 = *(const float4*)(xr + 8);
    float dot = v0.x*w1r[0] + v0.y*w1r[1] + v0.z*w1r[2]  + v0.w*w1r[3]
              + v1.x*w1r[4] + v1.y*w1r[5] + v1.z*w1r[6]  + v1.w*w1r[7]
              + v2.x*w1r[8] + v2.y*w1r[9] + v2.z*w1r[10] + v2.w*w1r[11];
    float q = gelu_f(dot);

    float acc[8];
    #pragma unroll
    for (int h = 0; h < NH; ++h) {
        acc[h]     = q * Wq[lane][h];
        acc[4 + h] = q * Wk[lane][h];
    }
    #pragma unroll
    for (int ofs = 32; ofs > 0; ofs >>= 1) {
        #pragma unroll
        for (int i = 0; i < 8; ++i)
            acc[i] += __shfl_xor(acc[i], ofs, 64);
    }
    if (lane < 8) {
        int h   = lane & 3;
        int isK = lane >> 2;
        int b   = (int)(row / N);
        int n   = (int)(row % N);
        float* dst = isK ? skT : sqT;
        dst[((long long)b * NH + h) * N + n] = acc[lane];
    }
}

// Score (R9 champion, unchanged): block owns a 256-quad j-window and IT=4
// consecutive rows; skT register-held; adj read (now cache-served), out
// written as 1KB wave bursts to the 8 bh streams.
__global__ __launch_bounds__(256) void score_kernel_tiled(
    const float* __restrict__ adj, const float* __restrict__ sqT,
    const float* __restrict__ skT, const float* __restrict__ a,
    float* __restrict__ out, int N)
{
    const float aadj = a[2 * DH];
    const int nq  = N >> 2;
    const int wpr = nq >> 8;                        // 256-quad windows per row
    const int ig = blockIdx.x / wpr;                // i-group
    const int w  = blockIdx.x - ig * wpr;           // window within row
    const int i0 = ig * IT;
    const int j0 = ((w << 8) + threadIdx.x) << 2;   // absolute column

    float4 sk[NB * NH];
    #pragma unroll
    for (int bh = 0; bh < NB * NH; ++bh)
        sk[bh] = *(const float4*)(skT + (long long)bh * N + j0);

    #pragma unroll
    for (int ii = 0; ii < IT; ++ii) {
        const int i = i0 + ii;
        float4 adj4 = *(const float4*)(adj + (long long)i * N + j0);
        const float a0 = adj4.x * aadj;
        const float a1 = adj4.y * aadj;
        const float a2 = adj4.z * aadj;
        const float a3 = adj4.w * aadj;

        #pragma unroll
        for (int bh = 0; bh < NB * NH; ++bh) {
            const float sq = sqT[(long long)bh * N + i];
            float4 o;
            o.x = gelu_f(sq + sk[bh].x + a0);
            o.y = gelu_f(sq + sk[bh].y + a1);
            o.z = gelu_f(sq + sk[bh].z + a2);
            o.w = gelu_f(sq + sk[bh].w + a3);
            *(float4*)(out + ((long long)bh * N + i) * N + j0) = o;
        }
    }
}

// Fallback (exact R4 kernel) for shapes where the tiled mapping doesn't divide.
__global__ __launch_bounds__(256) void score_kernel_flat(
    const float* __restrict__ adj, const float* __restrict__ sqT,
    const float* __restrict__ skT, const float* __restrict__ a,
    float* __restrict__ out, int N)
{
    const float aadj = a[2 * DH];
    const int nq = N >> 2;
    long long tid = (long long)blockIdx.x * blockDim.x + threadIdx.x;
    if (tid >= (long long)N * nq) return;
    const int i  = (int)(tid / nq);
    const int j0 = (int)(tid % nq) << 2;

    float4 adj4 = *(const float4*)(adj + (long long)i * N + j0);
    const float a0 = adj4.x * aadj;
    const float a1 = adj4.y * aadj;
    const float a2 = adj4.z * aadj;
    const float a3 = adj4.w * aadj;

    #pragma unroll
    for (int bh = 0; bh < NB * NH; ++bh) {
        const float sq = sqT[(long long)bh * N + i];
        float4 sk4 = *(const float4*)(skT + (long long)bh * N + j0);
        float4 o;
        o.x = gelu_f(sq + sk4.x + a0);
        o.y = gelu_f(sq + sk4.y + a1);
        o.z = gelu_f(sq + sk4.z + a2);
        o.w = gelu_f(sq + sk4.w + a3);
        *(float4*)(out + ((long long)bh * N + i) * N + j0) = o;
    }
}

extern "C" void kernel_launch(void* const* d_in, const int* in_sizes, int n_in,
                              void* d_out, int out_size, void* d_ws, size_t ws_size,
                              hipStream_t stream)
{
    const float* x   = (const float*)d_in[0];
    const float* adj = (const float*)d_in[1];
    const float* w1  = (const float*)d_in[2];
    const float* W2  = (const float*)d_in[3];
    const float* a   = (const float*)d_in[4];
    float* out = (float*)d_out;

    // N from adj (N*N elements); B fixed at 2 per reference setup.
    int N = 1;
    while ((long long)(N + 1) * (N + 1) <= (long long)in_sizes[1]) ++N;

    float* sqT = (float*)d_ws;                 // NB*NH*N floats
    float* skT = sqT + (size_t)NB * NH * N;    // NB*NH*N floats

    const int qkBlocks = (NB * N + 3) / 4;     // one wave per row, 4 waves/block
    const int pfBlocks = (N + 1) / 2;          // 2 adj rows per prefetch block
    qk_prefetch_kernel<<<qkBlocks + pfBlocks, 256, 0, stream>>>(
        x, adj, w1, W2, a, sqT, skT, N, qkBlocks);

    const int nq = N >> 2;
    if ((nq & 255) == 0 && (N % IT) == 0) {
        const int wpr = nq >> 8;
        const int blocks = (N / IT) * wpr;
        score_kernel_tiled<<<blocks, 256, 0, stream>>>(adj, sqT, skT, a, out, N);
    } else {
        const long long total = (long long)N * nq;
        score_kernel_flat<<<(int)((total + 255) / 256), 256, 0, stream>>>(adj, sqT, skT, a, out, N);
    }
}

// Round 11
// 34.344 us; speedup vs baseline: 1.0132x; 1.0132x over previous
//
#include <hip/hip_runtime.h>
#include <math.h>

#define NH 4    // heads
#define DH 8    // head dim
#define NF 64   // F
#define NT 12   // T
#define NB 2    // batch
#define IT 4    // i-rows tiled per score block

// Branchless exact-gelu: x * 0.5 * (1 + erf(x/sqrt(2))).
// erf via Abramowitz-Stegun 7.1.26 (max abs err 1.5e-7), no divergence.
__device__ __forceinline__ float gelu_f(float x) {
    const float s = x * 0.70710678118654752440f;
    const float z = __builtin_fabsf(s);
    const float t = __builtin_amdgcn_rcpf(fmaf(0.3275911f, z, 1.0f));
    float p = fmaf(1.061405429f, t, -1.453152027f);
    p = fmaf(p, t, 1.421413741f);
    p = fmaf(p, t, -0.284496736f);
    p = fmaf(p, t, 0.254829592f);
    p *= t;
    const float e = __builtin_amdgcn_exp2f(z * z * -1.44269504088896340736f); // exp(-z^2)
    const float erfa = fmaf(-p, e, 1.0f);                      // erf(|s|)
    const float erfv = __builtin_copysignf(erfa, s);           // erf(s)
    return 0.5f * x * (1.0f + erfv);
}

// One wave (64 lanes) per (b,n) row; lane = f. (R4 version — prefetch dropped,
// proven exactly neutral in R10.)
__global__ __launch_bounds__(256) void qk_kernel(
    const float* __restrict__ x, const float* __restrict__ w1,
    const float* __restrict__ W2, const float* __restrict__ a,
    float* __restrict__ sqT, float* __restrict__ skT, int N)
{
    __shared__ float Wq[NF][NH + 1];
    __shared__ float Wk[NF][NH + 1];
    const int t = threadIdx.x;

    {
        int f = t >> 2, h = t & 3;
        float accq = 0.f, acck = 0.f;
        #pragma unroll
        for (int k = 0; k < DH; ++k) {
            float w = W2[f * (NH * DH) + h * DH + k];
            accq += w * a[k];
            acck += w * a[DH + k];
        }
        Wq[f][h] = accq;
        Wk[f][h] = acck;
    }
    __syncthreads();

    float w1r[NT];
    #pragma unroll
    for (int i = 0; i < NT; ++i) w1r[i] = w1[i];

    const int wave = t >> 6;
    const int lane = t & 63;                      // = f
    const long long row = (long long)blockIdx.x * 4 + wave;   // in [0, NB*N)
    if (row >= (long long)NB * N) return;

    const float* xr = x + row * (NF * NT) + (long long)lane * NT;
    float4 v0 = *(const float4*)(xr);
    float4 v1 = *(const float4*)(xr + 4);
    float4 v2 = *(const float4*)(xr + 8);
    float dot = v0.x*w1r[0] + v0.y*w1r[1] + v0.z*w1r[2]  + v0.w*w1r[3]
              + v1.x*w1r[4] + v1.y*w1r[5] + v1.z*w1r[6]  + v1.w*w1r[7]
              + v2.x*w1r[8] + v2.y*w1r[9] + v2.z*w1r[10] + v2.w*w1r[11];
    float q = gelu_f(dot);

    float acc[8];
    #pragma unroll
    for (int h = 0; h < NH; ++h) {
        acc[h]     = q * Wq[lane][h];
        acc[4 + h] = q * Wk[lane][h];
    }
    #pragma unroll
    for (int ofs = 32; ofs > 0; ofs >>= 1) {
        #pragma unroll
        for (int i = 0; i < 8; ++i)
            acc[i] += __shfl_xor(acc[i], ofs, 64);
    }
    if (lane < 8) {
        int h   = lane & 3;
        int isK = lane >> 2;
        int b   = (int)(row / N);
        int n   = (int)(row % N);
        float* dst = isK ? skT : sqT;
        dst[((long long)b * NH + h) * N + n] = acc[lane];
    }
}

// R11: per-wave write-stream-count probe. Block = 4 waves, window = 256 quads
// (1024 cols) x IT=4 rows. adj window pre-scaled by aadj is staged ONCE in
// 16KB LDS (no added global/L2 traffic vs R4). Each wave handles 2 bh values:
// per-wave distinct far-apart write streams drop 8 -> 2, and each (bh,row)
// is written as a contiguous 4KB run. skT register-held per (wave,bh).
__global__ __launch_bounds__(256) void score_kernel_lds(
    const float* __restrict__ adj, const float* __restrict__ sqT,
    const float* __restrict__ skT, const float* __restrict__ a,
    float* __restrict__ out, int N)
{
    const float aadj = a[2 * DH];
    const int t   = threadIdx.x;
    const int nq  = N >> 2;
    const int wpr = nq >> 8;                        // 256-quad windows per row
    const int ig  = blockIdx.x / wpr;
    const int w   = blockIdx.x - ig * wpr;
    const int i0  = ig * IT;
    const int q0  = w << 8;                         // first quad of window

    __shared__ float adjS[IT][1024];                // 16KB, pre-scaled by aadj

    #pragma unroll
    for (int r = 0; r < IT; ++r) {
        float4 v = *(const float4*)(adj + (long long)(i0 + r) * N + ((q0 + t) << 2));
        float4 sv; sv.x = v.x * aadj; sv.y = v.y * aadj;
                   sv.z = v.z * aadj; sv.w = v.w * aadj;
        *(float4*)&adjS[r][t << 2] = sv;
    }
    __syncthreads();

    const int wave = t >> 6;
    const int lane = t & 63;

    #pragma unroll
    for (int bb = 0; bb < 2; ++bb) {
        const int bh = (wave << 1) + bb;

        float4 sk[4];
        #pragma unroll
        for (int k = 0; k < 4; ++k)
            sk[k] = *(const float4*)(skT + (long long)bh * N + ((q0 + lane + (k << 6)) << 2));

        #pragma unroll
        for (int ii = 0; ii < IT; ++ii) {
            const float sq = sqT[(long long)bh * N + i0 + ii];
            #pragma unroll
            for (int k = 0; k < 4; ++k) {
                const int qw = lane + (k << 6);     // quad within window
                const float* ar = &adjS[ii][qw << 2];
                float4 o;
                o.x = gelu_f(sq + sk[k].x + ar[0]);
                o.y = gelu_f(sq + sk[k].y + ar[1]);
                o.z = gelu_f(sq + sk[k].z + ar[2]);
                o.w = gelu_f(sq + sk[k].w + ar[3]);
                *(float4*)(out + ((long long)bh * N + i0 + ii) * N + ((q0 + qw) << 2)) = o;
            }
        }
    }
}

// Fallback (exact R4 kernel) for shapes where the tiled mapping doesn't divide.
__global__ __launch_bounds__(256) void score_kernel_flat(
    const float* __restrict__ adj, const float* __restrict__ sqT,
    const float* __restrict__ skT, const float* __restrict__ a,
    float* __restrict__ out, int N)
{
    const float aadj = a[2 * DH];
    const int nq = N >> 2;
    long long tid = (long long)blockIdx.x * blockDim.x + threadIdx.x;
    if (tid >= (long long)N * nq) return;
    const int i  = (int)(tid / nq);
    const int j0 = (int)(tid % nq) << 2;

    float4 adj4 = *(const float4*)(adj + (long long)i * N + j0);
    const float a0 = adj4.x * aadj;
    const float a1 = adj4.y * aadj;
    const float a2 = adj4.z * aadj;
    const float a3 = adj4.w * aadj;

    #pragma unroll
    for (int bh = 0; bh < NB * NH; ++bh) {
        const float sq = sqT[(long long)bh * N + i];
        float4 sk4 = *(const float4*)(skT + (long long)bh * N + j0);
        float4 o;
        o.x = gelu_f(sq + sk4.x + a0);
        o.y = gelu_f(sq + sk4.y + a1);
        o.z = gelu_f(sq + sk4.z + a2);
        o.w = gelu_f(sq + sk4.w + a3);
        *(float4*)(out + ((long long)bh * N + i) * N + j0) = o;
    }
}

extern "C" void kernel_launch(void* const* d_in, const int* in_sizes, int n_in,
                              void* d_out, int out_size, void* d_ws, size_t ws_size,
                              hipStream_t stream)
{
    const float* x   = (const float*)d_in[0];
    const float* adj = (const float*)d_in[1];
    const float* w1  = (const float*)d_in[2];
    const float* W2  = (const float*)d_in[3];
    const float* a   = (const float*)d_in[4];
    float* out = (float*)d_out;

    // N from adj (N*N elements); B fixed at 2 per reference setup.
    int N = 1;
    while ((long long)(N + 1) * (N + 1) <= (long long)in_sizes[1]) ++N;

    float* sqT = (float*)d_ws;                 // NB*NH*N floats
    float* skT = sqT + (size_t)NB * NH * N;    // NB*NH*N floats

    const int rows = NB * N;                   // one wave per row, 4 waves/block
    qk_kernel<<<(rows + 3) / 4, 256, 0, stream>>>(x, w1, W2, a, sqT, skT, N);

    const int nq = N >> 2;
    if ((nq & 255) == 0 && (N % IT) == 0) {
        const int wpr = nq >> 8;
        const int blocks = (N / IT) * wpr;     // 1024 at N=2048
        score_kernel_lds<<<blocks, 256, 0, stream>>>(adj, sqT, skT, a, out, N);
    } else {
        const long long total = (long long)N * nq;
        score_kernel_flat<<<(int)((total + 255) / 256), 256, 0, stream>>>(adj, sqT, skT, a, out, N);
    }
}